// Round 12
// baseline (390.592 us; speedup 1.0000x reference)
//
#include <hip/hip_runtime.h>

// DeepSeek MoE gate. Round 12: m201-style phase template on the fused R6 frame.
// BM=64 tok x 256 exp (full E, fused epilogue), BK=32 -> 224 kc-steps.
// 8 waves (2wr x 4wc), per-wave 32x64, acc 64 f32.
// Per kc-step TWO phases, each {ds_reads || 2 B-DMA gloads -> s_barrier ->
// setprio(1) 12-MFMA cluster setprio(0) -> s_barrier} (template barrier
// density: 1 per 8-K). B TRIPLE-buffered 3x32KB, global_load_lds issued 2
// steps ahead; end-of-step wait = COUNTED vmcnt(5) (B(T+2)+ra(T+2) in
// flight, never 0). A dbuf 2x8.3KB chunk-major, 1040-B padded stride
// (conflict-free frag reads); f32->f16 hi/lo convert sits between the two
// MFMA clusters (interleave). LDS 114.9 KB, 1 WG/CU, grid 256.

#define TTOK 16384
#define EEXP 256
#define HDIM 7168
#define BM 64
#define BK 32
#define NKC (HDIM / BK)  // 224
#define NTHR 512
#define BBASE(i) ((i) * 32768)       // B bufs: 3 x 32 KB @ 0/32K/64K
#define ABASE 98304                  // A bufs: 2 x 8320 B (hi 4160 + lo 4160)
#define APLANE 4160                  // 4 chunks x 1040 B (padded stride)
#define LDS_BYTES 114944             // 98304 + 2*8320; scores 65792 overlays

typedef __attribute__((ext_vector_type(4))) float f32x4;
typedef __attribute__((ext_vector_type(4))) _Float16 h4;
typedef __attribute__((ext_vector_type(8))) _Float16 h8;

__device__ __forceinline__ void gload_lds16(const void* g, void* l) {
  typedef const __attribute__((address_space(1))) unsigned int gu32;
  typedef __attribute__((address_space(3))) unsigned int lu32;
  __builtin_amdgcn_global_load_lds((gu32*)g, (lu32*)l, 16, 0, 0);
}

// ---------------------------------------------------------------------------
// Kernel 1: W[256][7168] f32 -> per-kc 32 KB blob: [eb 0..15][hi|lo][lane*16].
// Fragment: expert e = eb*16+(lane&15), k = kc*32+(lane>>4)*8+j.
// ---------------------------------------------------------------------------
__global__ __launch_bounds__(64) void pack_w_kernel(const float* __restrict__ W,
                                                    _Float16* __restrict__ blob) {
  const int kcg = blockIdx.x;    // 0..223
  const int eb = blockIdx.y;     // 0..15
  const int lane = threadIdx.x;  // 0..63
  const int e = eb * 16 + (lane & 15);
  const int k0 = kcg * 32 + (lane >> 4) * 8;
  const float* src = W + (size_t)e * HDIM + k0;
  h8 hi, lo;
#pragma unroll
  for (int j = 0; j < 8; ++j) {
    float x = src[j];
    _Float16 h = (_Float16)x;
    hi[j] = h;
    lo[j] = (_Float16)((x - (float)h) * 2048.0f);  // exact residual, out of denormals
  }
  char* dst = (char*)blob + ((size_t)kcg * 32 + eb * 2) * 1024 + lane * 16;
  *(h8*)dst = hi;
  *(h8*)(dst + 1024) = lo;
}

// ---------------------------------------------------------------------------
// Kernel 2: fused gate.
// ---------------------------------------------------------------------------
__global__ __launch_bounds__(NTHR, 1) void gate_kernel(
    const float* __restrict__ X, const _Float16* __restrict__ Wblob,
    const float* __restrict__ bias, float* __restrict__ outw,
    float* __restrict__ outi) {
  extern __shared__ char smem[];
  float (*scores)[EEXP + 1] = (float (*)[EEXP + 1])smem;  // epilogue overlay

  const int tid = threadIdx.x;
  const int lane = tid & 63;
  const int wid = tid >> 6;
  const int wr = wid >> 2;  // 0..1 : 32-token stripe
  const int wc = wid & 3;   // 0..3 : 64-expert stripe
  const int tok0 = blockIdx.x * BM;

  // A staging: thread -> row tid>>3 (0..63), quad aq = tid&7 (32 f32/row).
  const int arow = tid >> 3, aq = tid & 7;
  const float* asrc = X + (size_t)(tok0 + arow) * HDIM + aq * 4;
  const int awoff = (aq >> 1) * 1040 + arow * 16 + (aq & 1) * 8;

  f32x4 ra;  // A prefetch: 4 f32/thread

  f32x4 acc1[2][4], acc2[2][4];
#pragma unroll
  for (int m = 0; m < 2; ++m)
#pragma unroll
    for (int n = 0; n < 4; ++n) {
      acc1[m][n] = (f32x4){0.f, 0.f, 0.f, 0.f};
      acc2[m][n] = (f32x4){0.f, 0.f, 0.f, 0.f};
    }

  auto LOADA = [&](int T) { ra = *(const f32x4*)(asrc + (size_t)T * BK); };

  auto STAGEB2 = [&](int T, int buf, int half) {  // 2 of this wave's 4 granules
    const char* gs = (const char*)Wblob + (size_t)T * 32768 + lane * 16;
    char* lb = smem + BBASE(buf) + lane * 16;
    const int g0 = wid * 4 + half * 2;
    gload_lds16(gs + g0 * 1024, lb + g0 * 1024);
    gload_lds16(gs + (g0 + 1) * 1024, lb + (g0 + 1) * 1024);
  };

  auto ACONV = [&](int abuf) {  // convert ra -> f16 hi/lo, write padded plane
    h4 hi, lo;
#pragma unroll
    for (int j = 0; j < 4; ++j) {
      const float x = ra[j];
      const _Float16 h = (_Float16)x;
      hi[j] = h;
      lo[j] = (_Float16)((x - (float)h) * 2048.0f);
    }
    char* ap = smem + ABASE + abuf * (2 * APLANE);
    *(h4*)(ap + awoff) = hi;
    *(h4*)(ap + APLANE + awoff) = lo;
  };

#define MFMA_CLUSTER(NH, BB_, AHH, ALL)                                         \
  {                                                                             \
    __builtin_amdgcn_s_setprio(1);                                              \
    _Pragma("unroll") for (int n2 = 0; n2 < 2; ++n2) {                          \
      const int n_ = (NH) * 2 + n2;                                             \
      const int bo_ = ((wc * 4 + n_) * 2) * 1024 + lane * 16;                   \
      const h8 bh = *(const h8*)((BB_) + bo_);                                  \
      const h8 bl = *(const h8*)((BB_) + bo_ + 1024);                           \
      _Pragma("unroll") for (int m = 0; m < 2; ++m) {                           \
        acc1[m][n_] = __builtin_amdgcn_mfma_f32_16x16x32_f16(AHH[m], bh, acc1[m][n_], 0, 0, 0); \
        acc2[m][n_] = __builtin_amdgcn_mfma_f32_16x16x32_f16(AHH[m], bl, acc2[m][n_], 0, 0, 0); \
        acc2[m][n_] = __builtin_amdgcn_mfma_f32_16x16x32_f16(ALL[m], bh, acc2[m][n_], 0, 0, 0); \
      }                                                                         \
    }                                                                           \
    __builtin_amdgcn_s_setprio(0);                                              \
  }

  // Prologue: stage B0,B1; convert A0; leave B0..B1+ra1 pipeline primed.
  STAGEB2(0, 0, 0);
  STAGEB2(0, 0, 1);
  STAGEB2(1, 1, 0);
  STAGEB2(1, 1, 1);
  LOADA(0);
  ACONV(0);  // compiler waits ra0 (counted: 8 B-gloads older stay in flight)
  LOADA(1);
  asm volatile("s_waitcnt vmcnt(5) lgkmcnt(0)" ::: "memory");  // B0+ra0 landed
  __builtin_amdgcn_s_barrier();

  int pb = 0;
#pragma unroll 1
  for (int T = 0; T < NKC; ++T) {
    const int pa = T & 1;
    const bool p2 = (T + 2 < NKC);
    const char* ap = smem + ABASE + pa * (2 * APLANE);
    const char* bb = smem + BBASE(pb);

    // ---- phase 0: A-frag ds_reads + first half of B(T+2) DMA, then MFMA nh=0
    h8 ahf[2], alf[2];
#pragma unroll
    for (int m = 0; m < 2; ++m) {
      const int r_ = wr * 32 + m * 16 + (lane & 15);
      const int ao_ = (lane >> 4) * 1040 + r_ * 16;
      ahf[m] = *(const h8*)(ap + ao_);
      alf[m] = *(const h8*)(ap + APLANE + ao_);
    }
    if (p2) STAGEB2(T + 2, (T + 2) % 3, 0);
    __builtin_amdgcn_s_barrier();
    MFMA_CLUSTER(0, bb, ahf, alf);
    __builtin_amdgcn_s_barrier();

    // ---- phase 1: rest of B(T+2) DMA + A convert/store + MFMA nh=1
    if (p2) STAGEB2(T + 2, (T + 2) % 3, 1);
    if (T + 1 < NKC) ACONV(pa ^ 1);  // consumes ra(T+1); counted auto-wait
    if (p2) LOADA(T + 2);            // refill ra AFTER consumption (R10 rule)
    asm volatile("s_waitcnt lgkmcnt(0)" ::: "memory");  // drain A ds_writes
    if (p2)
      asm volatile("s_waitcnt vmcnt(5)" ::: "memory");  // B(T+2)x4+ra(T+2) fly
    else
      asm volatile("s_waitcnt vmcnt(0)" ::: "memory");  // tail steps only
    __builtin_amdgcn_s_barrier();
    MFMA_CLUSTER(1, bb, ahf, alf);
    __builtin_amdgcn_s_barrier();

    pb = (pb == 2) ? 0 : pb + 1;
  }

  __syncthreads();  // full drain before scores overlay the staging LDS

  // scores = sigmoid(logit) + bias  -> LDS [64][257]
  // C/D layout: col = lane&15, row = (lane>>4)*4 + reg
#pragma unroll
  for (int m = 0; m < 2; ++m)
#pragma unroll
    for (int n = 0; n < 4; ++n) {
      const int e = wc * 64 + n * 16 + (lane & 15);
      const float b = bias[e];
      const int t0 = wr * 32 + m * 16 + (lane >> 4) * 4;
#pragma unroll
      for (int r = 0; r < 4; ++r) {
        const float logit = acc1[m][n][r] + acc2[m][n][r] * (1.0f / 2048.0f);
        scores[t0 + r][e] = 1.0f / (1.0f + expf(-logit)) + b;
      }
    }
  __syncthreads();

  // Per-token top-k: 8 tokens per wave, one active lane per token (64 total).
  if ((lane & 7) == 0) {
    const int t = wid * 8 + (lane >> 3);  // 0..63
    const float* sc = scores[t];

    float gmax[8];
#pragma unroll
    for (int g = 0; g < 8; ++g) {
      float mx = -1e30f;
      for (int j = 0; j < 32; ++j) mx = fmaxf(mx, sc[g * 32 + j]);
      gmax[g] = mx;
    }
    // top-4 groups (strict > keeps lowest index on ties, matching lax.top_k)
    unsigned selmask = 0;
    for (int it = 0; it < 4; ++it) {
      float best = -1e30f;
      int bi = 0;
      for (int g = 0; g < 8; ++g)
        if (!((selmask >> g) & 1) && gmax[g] > best) {
          best = gmax[g];
          bi = g;
        }
      selmask |= 1u << bi;
    }
    // stable top-8 over masked scores (masked-out groups contribute 0.0)
    float vals[8];
    int idx[8];
#pragma unroll
    for (int j = 0; j < 8; ++j) {
      vals[j] = -1e30f;
      idx[j] = 0;
    }
    for (int e = 0; e < 256; ++e) {
      const float v = ((selmask >> (e >> 5)) & 1) ? sc[e] : 0.0f;
      if (v > vals[7]) {
        int p = 7;
        while (p > 0 && v > vals[p - 1]) {
          vals[p] = vals[p - 1];
          idx[p] = idx[p - 1];
          --p;
        }
        vals[p] = v;
        idx[p] = e;
      }
    }
    float ssum = 0.0f;
#pragma unroll
    for (int j = 0; j < 8; ++j) ssum += vals[j];
    const float den = ssum + 1e-6f;
    const long tg = (long)tok0 + t;
#pragma unroll
    for (int j = 0; j < 8; ++j) {
      outw[tg * 8 + j] = vals[j] / den;
      outi[tg * 8 + j] = (float)idx[j];  // indices written as f32 values
    }
  }
}

extern "C" void kernel_launch(void* const* d_in, const int* in_sizes, int n_in,
                              void* d_out, int out_size, void* d_ws, size_t ws_size,
                              hipStream_t stream) {
  const float* X = (const float*)d_in[0];     // [16384,7168] f32
  const float* W = (const float*)d_in[1];     // [256,7168] f32
  const float* bias = (const float*)d_in[2];  // [256] f32

  _Float16* wblob = (_Float16*)d_ws;  // 7.34 MB fragment-major hi/lo blob

  float* outw = (float*)d_out;            // [16384,8]
  float* outi = outw + (size_t)TTOK * 8;  // [16384,8] as f32 values

  hipFuncSetAttribute((const void*)gate_kernel,
                      hipFuncAttributeMaxDynamicSharedMemorySize, LDS_BYTES);

  pack_w_kernel<<<dim3(NKC, EEXP / 16), 64, 0, stream>>>(W, wblob);
  gate_kernel<<<TTOK / BM, NTHR, LDS_BYTES, stream>>>(X, wblob, bias, outw, outi);
}

// Round 13
// 374.263 us; speedup vs baseline: 1.0436x; 1.0436x over previous
//
#include <hip/hip_runtime.h>

// DeepSeek MoE gate. Round 13 = Round 6 (best, 286us) with address hoisting:
// all LDS/global address streams precomputed into per-lane base pointers
// before the K-loop; main loop manually unrolled x2 so buffer indices are
// compile-time and every ds/global access is base + constant offset.
// Everything else (layouts, sync, tile shape) is R6 verbatim:
// BM=64 x E=256, BK=64, 8 waves (2wr x 4wc), B via global_load_lds into
// 2x64KB LDS, A reg-staged f32->f16 hi/lo into 2x16KB (XOR chunk swizzle),
// one vmcnt(0)+lgkmcnt(0)+barrier per step, LDS 160KB, grid 256.

#define TTOK 16384
#define EEXP 256
#define HDIM 7168
#define BM 64
#define BK 64
#define NSTEP (HDIM / BK)  // 112
#define NTHR 512
#define LDS_BYTES 163840   // B: 2x65536 @0; A: 2x16384 @131072
#define ABASE 131072

typedef __attribute__((ext_vector_type(4))) float f32x4;
typedef __attribute__((ext_vector_type(8))) _Float16 h8;

__device__ __forceinline__ void gload_lds16(const void* g, void* l) {
  typedef const __attribute__((address_space(1))) unsigned int gu32;
  typedef __attribute__((address_space(3))) unsigned int lu32;
  __builtin_amdgcn_global_load_lds((gu32*)g, (lu32*)l, 16, 0, 0);
}

// ---------------------------------------------------------------------------
// Kernel 1: W[256][7168] f32 -> fragment-major f16 hi/lo blob, per-K-step
// (64K) contiguous 64KB. Byte offset = (kcg*32 + eb*2 + hl)*1024 + lane*16;
// fragment [kcg][eb][hl] : expert e = eb*16+(lane&15), k = kcg*32+(lane>>4)*8+j.
// ---------------------------------------------------------------------------
__global__ __launch_bounds__(64) void pack_w_kernel(const float* __restrict__ W,
                                                    _Float16* __restrict__ blob) {
  const int kcg = blockIdx.x;    // 0..223
  const int eb = blockIdx.y;     // 0..15
  const int lane = threadIdx.x;  // 0..63
  const int e = eb * 16 + (lane & 15);
  const int k0 = kcg * 32 + (lane >> 4) * 8;
  const float* src = W + (size_t)e * HDIM + k0;
  h8 hi, lo;
#pragma unroll
  for (int j = 0; j < 8; ++j) {
    float x = src[j];
    _Float16 h = (_Float16)x;
    hi[j] = h;
    lo[j] = (_Float16)((x - (float)h) * 2048.0f);  // exact residual, out of denormals
  }
  char* dst = (char*)blob + ((size_t)kcg * 32 + eb * 2) * 1024 + lane * 16;
  *(h8*)dst = hi;
  *(h8*)(dst + 1024) = lo;
}

// ---------------------------------------------------------------------------
// Kernel 2: fused gate.
// ---------------------------------------------------------------------------
__global__ __launch_bounds__(NTHR, 1) void gate_kernel(
    const float* __restrict__ X, const _Float16* __restrict__ Wblob,
    const float* __restrict__ bias, float* __restrict__ outw,
    float* __restrict__ outi) {
  extern __shared__ char smem[];
  float (*scores)[EEXP + 1] = (float (*)[EEXP + 1])smem;  // epilogue overlay

  const int tid = threadIdx.x;
  const int lane = tid & 63;
  const int wid = tid >> 6;
  const int wr = wid >> 2;  // 0..1 : 32-token stripe
  const int wc = wid & 3;   // 0..3 : 64-expert stripe
  const int tok0 = blockIdx.x * BM;

  // ---- precomputed per-lane base pointers (hoisted out of the K-loop) ----
  // A staging (write): thread -> row tid>>3, k-chunk-of-8 = tid&7.
  const int arow = tid >> 3, ac8 = tid & 7;
  const float* ap = X + (size_t)(tok0 + arow) * HDIM + ac8 * 8;  // running ptr
  char* const aW = smem + ABASE + arow * 128 + ((ac8 ^ (arow & 7)) << 4);
  // A fragment reads: XOR term t_S obeys t_S1 = t_S0 ^ 4 (lane>>4 < 4).
  {
  }
  const int t0x = ((lane >> 4) ^ (lane & 7));
  const char* const aRS0 =
      smem + ABASE + (wr * 32 + (lane & 15)) * 128 + (t0x << 4);
  const char* const aRS1 =
      smem + ABASE + (wr * 32 + (lane & 15)) * 128 + ((t0x ^ 4) << 4);
  // B reads: base covers wc and lane; +S*32768 +n*2048 +hl*1024 immediates.
  const char* const bR0 = smem + wc * 8192 + lane * 16;
  const char* const bR1 = bR0 + 65536;
  // B DMA: granule gb = i*8 + wid; src/dst = base + i*8192 (+T*65536 on src).
  const char* gBp = (const char*)Wblob + wid * 1024 + lane * 16;  // running ptr
  char* const sB = smem + wid * 1024 + lane * 16;

  f32x4 ra0, ra1;  // A prefetch registers

  f32x4 acc1[2][4], acc2[2][4];
#pragma unroll
  for (int m = 0; m < 2; ++m)
#pragma unroll
    for (int n = 0; n < 4; ++n) {
      acc1[m][n] = (f32x4){0.f, 0.f, 0.f, 0.f};
      acc2[m][n] = (f32x4){0.f, 0.f, 0.f, 0.f};
    }

#define LOADA(OFS)                                \
  {                                               \
    ra0 = *(const f32x4*)(ap + (OFS));            \
    ra1 = *(const f32x4*)(ap + (OFS) + 4);        \
  }

#define STAGEB(GOFS, BUF)                                             \
  {                                                                   \
    _Pragma("unroll") for (int i = 0; i < 8; ++i)                     \
        gload_lds16(gBp + (GOFS) + i * 8192,                          \
                    sB + (BUF) * 65536 + i * 8192);                   \
  }

#define ACONV(BUF)                                                    \
  {                                                                   \
    h8 hi_, lo_;                                                      \
    _Pragma("unroll") for (int j = 0; j < 4; ++j) {                   \
      float x_ = ra0[j];                                              \
      _Float16 h_ = (_Float16)x_;                                     \
      hi_[j] = h_;                                                    \
      lo_[j] = (_Float16)((x_ - (float)h_) * 2048.0f);                \
      float y_ = ra1[j];                                              \
      _Float16 g_ = (_Float16)y_;                                     \
      hi_[4 + j] = g_;                                                \
      lo_[4 + j] = (_Float16)((y_ - (float)g_) * 2048.0f);            \
    }                                                                 \
    *(h8*)(aW + (BUF) * 16384) = hi_;                                 \
    *(h8*)(aW + (BUF) * 16384 + 8192) = lo_;                          \
  }

#define PHASE(S, BUF)                                                           \
  {                                                                             \
    const char* ar_ = (S) ? aRS1 : aRS0;                                        \
    const char* br_ = (BUF) ? bR1 : bR0;                                        \
    h8 ah[2], al[2];                                                            \
    ah[0] = *(const h8*)(ar_ + (BUF) * 16384);                                  \
    al[0] = *(const h8*)(ar_ + (BUF) * 16384 + 8192);                           \
    ah[1] = *(const h8*)(ar_ + (BUF) * 16384 + 2048);                           \
    al[1] = *(const h8*)(ar_ + (BUF) * 16384 + 8192 + 2048);                    \
    h8 bh[4], bl[4];                                                            \
    _Pragma("unroll") for (int n = 0; n < 4; ++n) {                             \
      bh[n] = *(const h8*)(br_ + (S) * 32768 + n * 2048);                       \
      bl[n] = *(const h8*)(br_ + (S) * 32768 + n * 2048 + 1024);                \
    }                                                                           \
    _Pragma("unroll") for (int n = 0; n < 4; ++n)                               \
        _Pragma("unroll") for (int m = 0; m < 2; ++m) {                         \
      acc1[m][n] = __builtin_amdgcn_mfma_f32_16x16x32_f16(ah[m], bh[n], acc1[m][n], 0, 0, 0); \
      acc2[m][n] = __builtin_amdgcn_mfma_f32_16x16x32_f16(ah[m], bl[n], acc2[m][n], 0, 0, 0); \
      acc2[m][n] = __builtin_amdgcn_mfma_f32_16x16x32_f16(al[m], bh[n], acc2[m][n], 0, 0, 0); \
    }                                                                           \
  }

#define STEP_END()                                              \
  {                                                             \
    asm volatile("s_waitcnt vmcnt(0) lgkmcnt(0)" ::: "memory"); \
    __builtin_amdgcn_s_barrier();                               \
  }

  // Prologue: stage step 0 into buffer 0 (R6 order: LOADA before DMA so the
  // ACONV auto-wait is counted).
  LOADA(0);
  STAGEB(0, 0);
  ACONV(0);
  STEP_END();

  // Main loop: 2 steps per iteration (buf0 then buf1), all offsets constant.
#pragma unroll 1
  for (int it = 0; it < NSTEP / 2; ++it) {
    // ---- step T=2it (compute buf0; prefetch T+1 -> buf1)
    LOADA(BK);            // ra <- step 2it+1
    STAGEB(65536, 1);     // B DMA step 2it+1 -> buf1
    PHASE(0, 0);
    PHASE(1, 0);
    ACONV(1);             // waits ra (counted: 8 DMA older... DMA newer; waits all ra)
    STEP_END();
    // ---- step T=2it+1 (compute buf1; prefetch T+2 -> buf0)
    if (it + 1 < NSTEP / 2) {
      LOADA(2 * BK);        // ra <- step 2it+2
      STAGEB(131072, 0);    // B DMA step 2it+2 -> buf0
      PHASE(0, 1);
      PHASE(1, 1);
      ACONV(0);
      STEP_END();
      ap += 2 * BK;
      gBp += 131072;
    } else {
      PHASE(0, 1);
      PHASE(1, 1);
      STEP_END();
    }
  }

  __syncthreads();  // full drain before scores overlay the staging LDS

  // scores = sigmoid(logit) + bias  -> LDS [64][257]
  // C/D layout: col = lane&15, row = (lane>>4)*4 + reg
#pragma unroll
  for (int m = 0; m < 2; ++m)
#pragma unroll
    for (int n = 0; n < 4; ++n) {
      const int e = (wc * 4 + n) * 16 + (lane & 15);
      const float b = bias[e];
      const int t0 = wr * 32 + m * 16 + (lane >> 4) * 4;
#pragma unroll
      for (int r = 0; r < 4; ++r) {
        const float logit = acc1[m][n][r] + acc2[m][n][r] * (1.0f / 2048.0f);
        scores[t0 + r][e] = 1.0f / (1.0f + expf(-logit)) + b;
      }
    }
  __syncthreads();

  // Per-token top-k: 8 tokens per wave, one active lane per token (64 total).
  if ((lane & 7) == 0) {
    const int t = wid * 8 + (lane >> 3);  // 0..63
    const float* sc = scores[t];

    float gmax[8];
#pragma unroll
    for (int g = 0; g < 8; ++g) {
      float mx = -1e30f;
      for (int j = 0; j < 32; ++j) mx = fmaxf(mx, sc[g * 32 + j]);
      gmax[g] = mx;
    }
    // top-4 groups (strict > keeps lowest index on ties, matching lax.top_k)
    unsigned selmask = 0;
    for (int it2 = 0; it2 < 4; ++it2) {
      float best = -1e30f;
      int bi = 0;
      for (int g = 0; g < 8; ++g)
        if (!((selmask >> g) & 1) && gmax[g] > best) {
          best = gmax[g];
          bi = g;
        }
      selmask |= 1u << bi;
    }
    // stable top-8 over masked scores (masked-out groups contribute 0.0)
    float vals[8];
    int idx[8];
#pragma unroll
    for (int j = 0; j < 8; ++j) {
      vals[j] = -1e30f;
      idx[j] = 0;
    }
    for (int e = 0; e < 256; ++e) {
      const float v = ((selmask >> (e >> 5)) & 1) ? sc[e] : 0.0f;
      if (v > vals[7]) {
        int p = 7;
        while (p > 0 && v > vals[p - 1]) {
          vals[p] = vals[p - 1];
          idx[p] = idx[p - 1];
          --p;
        }
        vals[p] = v;
        idx[p] = e;
      }
    }
    float ssum = 0.0f;
#pragma unroll
    for (int j = 0; j < 8; ++j) ssum += vals[j];
    const float den = ssum + 1e-6f;
    const long tg = (long)tok0 + t;
#pragma unroll
    for (int j = 0; j < 8; ++j) {
      outw[tg * 8 + j] = vals[j] / den;
      outi[tg * 8 + j] = (float)idx[j];  // indices written as f32 values
    }
  }
}

extern "C" void kernel_launch(void* const* d_in, const int* in_sizes, int n_in,
                              void* d_out, int out_size, void* d_ws, size_t ws_size,
                              hipStream_t stream) {
  const float* X = (const float*)d_in[0];     // [16384,7168] f32
  const float* W = (const float*)d_in[1];     // [256,7168] f32
  const float* bias = (const float*)d_in[2];  // [256] f32

  _Float16* wblob = (_Float16*)d_ws;  // 7.34 MB fragment-major hi/lo blob

  float* outw = (float*)d_out;            // [16384,8]
  float* outi = outw + (size_t)TTOK * 8;  // [16384,8] as f32 values

  hipFuncSetAttribute((const void*)gate_kernel,
                      hipFuncAttributeMaxDynamicSharedMemorySize, LDS_BYTES);

  pack_w_kernel<<<dim3(HDIM / 32, EEXP / 16), 64, 0, stream>>>(W, wblob);
  gate_kernel<<<TTOK / BM, NTHR, LDS_BYTES, stream>>>(X, wblob, bias, outw, outi);
}

// Round 14
// 364.143 us; speedup vs baseline: 1.0726x; 1.0278x over previous
//
#include <hip/hip_runtime.h>

// DeepSeek MoE gate. Round 14: m97 RESIDENCY clone — the overlap mechanism is
// 3 independent co-resident WGs per CU (m114), not intra-WG scheduling.
// Grid 1024 = 256 tb x 2 ehalf x 2 kslice; WG = 256 thr (4 waves, 2wr x 2wc,
// 32x64 wave tiles); BK=32; LDS 48 KB (B dbuf 2x16K + A dbuf 2x8K) -> 3 WGs/CU;
// launch_bounds(256,4) -> 128-VGPR cap (natural ~115, no squeeze).
// Plain __syncthreads, compiler-managed waits (m97 style, no asm vmcnt).
// B fragment blob DMA'd via global_load_lds w=16; A reg-staged f32->f16 hi/lo.
// Partial f32 logits -> ws; proven epilogue kernel does sum->sigmoid->top-k.

#define TTOK 16384
#define EEXP 256
#define HDIM 7168
#define BM 64
#define BE 128
#define BK 32
#define SPLITK 2
#define KSLICE (HDIM / SPLITK)  // 3584
#define NSTEP (KSLICE / BK)     // 112
#define NTHR 256
#define LDS_BYTES 49152         // B0,B1 @0,16K; A0,A1 @32K,40K (hi 4K + lo 4K)
#define ABASE 32768
#define EPI_LDS (64 * 257 * 4)  // 65792

typedef __attribute__((ext_vector_type(4))) float f32x4;
typedef __attribute__((ext_vector_type(8))) _Float16 h8;

__device__ __forceinline__ void gload_lds16(const void* g, void* l) {
  typedef const __attribute__((address_space(1))) unsigned int gu32;
  typedef __attribute__((address_space(3))) unsigned int lu32;
  __builtin_amdgcn_global_load_lds((gu32*)g, (lu32*)l, 16, 0, 0);
}

// ---------------------------------------------------------------------------
// Kernel 1: W -> blob[slice][ehalf][kc'][eb'][hi/lo][lane]: per (slice,ehalf,
// kc) a 16 KB contiguous chunk of 16 fragment-granules (8 eb' x hi/lo).
// Fragment: expert e = eb*16+(lane&15), k = kc*32+(lane>>4)*8+j.
// ---------------------------------------------------------------------------
__global__ __launch_bounds__(64) void pack_w_kernel(const float* __restrict__ W,
                                                    _Float16* __restrict__ blob) {
  const int kcg = blockIdx.x;    // 0..223
  const int eb = blockIdx.y;     // 0..15
  const int lane = threadIdx.x;  // 0..63
  const int e = eb * 16 + (lane & 15);
  const int k0 = kcg * 32 + (lane >> 4) * 8;
  const float* src = W + (size_t)e * HDIM + k0;
  h8 hi, lo;
#pragma unroll
  for (int j = 0; j < 8; ++j) {
    float x = src[j];
    _Float16 h = (_Float16)x;
    hi[j] = h;
    lo[j] = (_Float16)((x - (float)h) * 2048.0f);  // exact residual, out of denormals
  }
  const int slice = kcg / NSTEP, kcl = kcg % NSTEP;
  const int ehalf = eb >> 3, ebl = eb & 7;
  char* dst = (char*)blob + ((size_t)(slice * 2 + ehalf) * NSTEP + kcl) * 16384 +
              (ebl * 2) * 1024 + lane * 16;
  *(h8*)dst = hi;
  *(h8*)(dst + 1024) = lo;
}

// ---------------------------------------------------------------------------
// Kernel 2: split-K, split-E GEMM -> f32 partial logits.
// ---------------------------------------------------------------------------
__global__ __launch_bounds__(NTHR, 4) void gate_kernel(
    const float* __restrict__ X, const _Float16* __restrict__ Wblob,
    float* __restrict__ part) {
  extern __shared__ char smem[];

  const int bid = blockIdx.x;                    // 0..1023
  const int slice = (bid & 7) >> 2;              // XCDs 0-3: slice 0; 4-7: slice 1
  const int ehalf = (bid >> 3) & 1;              // paired ehalfs 8 apart -> same XCD
  const int tb = ((bid >> 4) << 2) | (bid & 3);  // 0..255
  const int tok0 = tb * BM;
  const int kbase = slice * KSLICE;
  const char* blobs = (const char*)Wblob +
                      ((size_t)(slice * 2 + ehalf) * NSTEP) * 16384;

  const int tid = threadIdx.x;
  const int lane = tid & 63;
  const int wid = tid >> 6;  // 0..3
  const int wr = wid >> 1;   // 0..1 : 32-token stripe
  const int wc = wid & 1;    // 0..1 : 64-expert stripe

  f32x4 ra[2];  // A prefetch: 8 f32/thread (one k-chunk of 8)

  f32x4 acc1[2][4], acc2[2][4];
#pragma unroll
  for (int m = 0; m < 2; ++m)
#pragma unroll
    for (int n = 0; n < 4; ++n) {
      acc1[m][n] = (f32x4){0.f, 0.f, 0.f, 0.f};
      acc2[m][n] = (f32x4){0.f, 0.f, 0.f, 0.f};
    }

  auto LOADA = [&](int T) {
    const float* p = X + (size_t)(tok0 + (tid >> 2)) * HDIM + kbase + T * BK +
                     (tid & 3) * 8;
    ra[0] = *(const f32x4*)p;
    ra[1] = *(const f32x4*)(p + 4);
  };

  auto STAGEB = [&](int T, int buf) {  // 16 granules of 1 KB; 4 per wave
    const char* gs = blobs + (size_t)T * 16384 + lane * 16;
    char* lb = smem + buf * 16384 + lane * 16;
#pragma unroll
    for (int i = 0; i < 4; ++i) {
      const int gb = wid * 4 + i;
      gload_lds16(gs + gb * 1024, lb + gb * 1024);
    }
  };

  auto STOREA = [&](int buf) {  // A plane: [4 kc-chunk][64 row][16B]; hi|lo
    const int row = tid >> 2, q = tid & 3;
    h8 hi, lo;
#pragma unroll
    for (int half = 0; half < 2; ++half) {
      const f32x4 v = ra[half];
#pragma unroll
      for (int j = 0; j < 4; ++j) {
        const float x = v[j];
        const _Float16 h = (_Float16)x;
        hi[half * 4 + j] = h;
        lo[half * 4 + j] = (_Float16)((x - (float)h) * 2048.0f);
      }
    }
    char* ap = smem + ABASE + buf * 8192;
    *(h8*)(ap + q * 1024 + row * 16) = hi;
    *(h8*)(ap + 4096 + q * 1024 + row * 16) = lo;
  };

  auto PHASE = [&](int buf) {
    const char* ap = smem + ABASE + buf * 8192;
    const char* bb = smem + buf * 16384;
    h8 ah[2], al[2];
#pragma unroll
    for (int m = 0; m < 2; ++m) {
      const int r_ = wr * 32 + m * 16 + (lane & 15);
      const int ao_ = (lane >> 4) * 1024 + r_ * 16;
      ah[m] = *(const h8*)(ap + ao_);
      al[m] = *(const h8*)(ap + 4096 + ao_);
    }
    __builtin_amdgcn_s_setprio(1);
#pragma unroll
    for (int n = 0; n < 4; ++n) {  // B frags just-in-time
      const int bo_ = ((wc * 4 + n) * 2) * 1024 + lane * 16;
      const h8 bh = *(const h8*)(bb + bo_);
      const h8 bl = *(const h8*)(bb + bo_ + 1024);
#pragma unroll
      for (int m = 0; m < 2; ++m) {
        acc1[m][n] = __builtin_amdgcn_mfma_f32_16x16x32_f16(ah[m], bh, acc1[m][n], 0, 0, 0);
        acc2[m][n] = __builtin_amdgcn_mfma_f32_16x16x32_f16(ah[m], bl, acc2[m][n], 0, 0, 0);
        acc2[m][n] = __builtin_amdgcn_mfma_f32_16x16x32_f16(al[m], bh, acc2[m][n], 0, 0, 0);
      }
    }
    __builtin_amdgcn_s_setprio(0);
  };

  // Prologue (R6-proven order): ra oldest in FIFO, then DMA; STOREA's
  // compiler-inserted wait retires ra while the DMA stays in flight; the
  // __syncthreads drain then guarantees B0 residency.
  LOADA(0);
  STAGEB(0, 0);
  STOREA(0);
  __syncthreads();

  int buf = 0;
#pragma unroll 1
  for (int T = 0; T < NSTEP; ++T) {
    const bool pf = (T + 1 < NSTEP);
    if (pf) {
      LOADA(T + 1);           // ra loads first (oldest)
      STAGEB(T + 1, buf ^ 1); // 16 result-less DMA, land during PHASE
    }
    PHASE(buf);
    if (pf) STOREA(buf ^ 1);  // waits ra only; DMA still flying
    __syncthreads();          // full drain (m97 tax) -> next buffers ready
    buf ^= 1;
  }

  // Partial f32 logits: part[slice][token][expert(256)], our 128-col half.
  // C/D layout: col = lane&15, row = (lane>>4)*4 + reg.
  float* pbase = part + ((size_t)slice * TTOK + tok0) * EEXP + ehalf * BE;
#pragma unroll
  for (int m = 0; m < 2; ++m)
#pragma unroll
    for (int n = 0; n < 4; ++n) {
      const int e = wc * 64 + n * 16 + (lane & 15);
      const int t0 = wr * 32 + m * 16 + (lane >> 4) * 4;
#pragma unroll
      for (int r = 0; r < 4; ++r)
        pbase[(size_t)(t0 + r) * EEXP + e] =
            acc1[m][n][r] + acc2[m][n][r] * (1.0f / 2048.0f);
    }
}

// ---------------------------------------------------------------------------
// Kernel 3: epilogue. 64 tokens/WG: sum 2 partials, sigmoid+bias -> LDS,
// then 64 lanes do per-token group-limited top-k. (Proven R3/R7/R8/R10.)
// ---------------------------------------------------------------------------
__global__ __launch_bounds__(256) void epilogue_kernel(
    const float* __restrict__ part, const float* __restrict__ bias,
    float* __restrict__ outw, float* __restrict__ outi) {
  extern __shared__ float sc[];  // [64][257]
  const int tid = threadIdx.x;
  const long t0 = (long)blockIdx.x * 64;

  const int e4 = (tid & 63) * 4;
  const int rsub = tid >> 6;
  const f32x4 bv = *(const f32x4*)(bias + e4);
#pragma unroll
  for (int rr = 0; rr < 16; ++rr) {
    const int row = rr * 4 + rsub;
    const f32x4 a = *(const f32x4*)(part + (t0 + row) * EEXP + e4);
    const f32x4 c = *(const f32x4*)(part + ((long)TTOK + t0 + row) * EEXP + e4);
#pragma unroll
    for (int j = 0; j < 4; ++j) {
      const float v = a[j] + c[j];
      sc[row * 257 + e4 + j] = 1.0f / (1.0f + expf(-v)) + bv[j];
    }
  }
  __syncthreads();

  if (tid < 64) {
    const float* s = sc + tid * 257;
    float gmax[8];
#pragma unroll
    for (int g = 0; g < 8; ++g) {
      float mx = -1e30f;
      for (int j = 0; j < 32; ++j) mx = fmaxf(mx, s[g * 32 + j]);
      gmax[g] = mx;
    }
    // top-4 groups (strict > keeps lowest index on ties, matching lax.top_k)
    unsigned selmask = 0;
    for (int it = 0; it < 4; ++it) {
      float best = -1e30f;
      int bi = 0;
      for (int g = 0; g < 8; ++g)
        if (!((selmask >> g) & 1) && gmax[g] > best) {
          best = gmax[g];
          bi = g;
        }
      selmask |= 1u << bi;
    }
    // stable top-8 over masked scores (masked-out groups contribute 0.0)
    float vals[8];
    int idx[8];
#pragma unroll
    for (int j = 0; j < 8; ++j) {
      vals[j] = -1e30f;
      idx[j] = 0;
    }
    for (int e = 0; e < 256; ++e) {
      const float v = ((selmask >> (e >> 5)) & 1) ? s[e] : 0.0f;
      if (v > vals[7]) {
        int p = 7;
        while (p > 0 && v > vals[p - 1]) {
          vals[p] = vals[p - 1];
          idx[p] = idx[p - 1];
          --p;
        }
        vals[p] = v;
        idx[p] = e;
      }
    }
    float ssum = 0.0f;
#pragma unroll
    for (int j = 0; j < 8; ++j) ssum += vals[j];
    const float den = ssum + 1e-6f;
    const long tg = t0 + tid;
#pragma unroll
    for (int j = 0; j < 8; ++j) {
      outw[tg * 8 + j] = vals[j] / den;
      outi[tg * 8 + j] = (float)idx[j];  // indices written as f32 values
    }
  }
}

extern "C" void kernel_launch(void* const* d_in, const int* in_sizes, int n_in,
                              void* d_out, int out_size, void* d_ws, size_t ws_size,
                              hipStream_t stream) {
  const float* X = (const float*)d_in[0];     // [16384,7168] f32
  const float* W = (const float*)d_in[1];     // [256,7168] f32
  const float* bias = (const float*)d_in[2];  // [256] f32

  _Float16* wblob = (_Float16*)d_ws;                              // 7.34 MB
  float* part = (float*)((char*)d_ws + (size_t)EEXP * HDIM * 4);  // 33.6 MB

  float* outw = (float*)d_out;            // [16384,8]
  float* outi = outw + (size_t)TTOK * 8;  // [16384,8] as f32 values

  hipFuncSetAttribute((const void*)gate_kernel,
                      hipFuncAttributeMaxDynamicSharedMemorySize, LDS_BYTES);
  hipFuncSetAttribute((const void*)epilogue_kernel,
                      hipFuncAttributeMaxDynamicSharedMemorySize, EPI_LDS);

  pack_w_kernel<<<dim3(HDIM / 32, EEXP / 16), 64, 0, stream>>>(W, wblob);
  gate_kernel<<<SPLITK * 2 * (TTOK / BM), NTHR, LDS_BYTES, stream>>>(X, wblob, part);
  epilogue_kernel<<<TTOK / 64, 256, EPI_LDS, stream>>>(part, bias, outw, outi);
}